// Round 11
// baseline (49.325 us; speedup 1.0000x reference)
//
#include <hip/hip_runtime.h>

constexpr int K  = 3;
constexpr int Hc = 512, Wc = 512, Bc = 8;
constexpr int HWc = Hc * Wc;

typedef __attribute__((ext_vector_type(2))) unsigned int u32x2;
typedef __attribute__((ext_vector_type(4))) unsigned int u32x4;

__device__ __forceinline__ float bl32(__amdgpu_buffer_rsrc_t r, int vo, int so) {
    return __uint_as_float(__builtin_amdgcn_raw_buffer_load_b32(r, vo, so, 0));
}
__device__ __forceinline__ u32x2 bl64(__amdgpu_buffer_rsrc_t r, int vo, int so) {
    return __builtin_amdgcn_raw_buffer_load_b64(r, vo, so, 0);
}
__device__ __forceinline__ u32x4 bl128(__amdgpu_buffer_rsrc_t r, int vo, int so) {
    return __builtin_amdgcn_raw_buffer_load_b128(r, vo, so, 0);
}
__device__ __forceinline__ unsigned umax2(unsigned a, unsigned b) { return a > b ? a : b; }
__device__ __forceinline__ unsigned vmax4(u32x4 v) {
    return umax2(umax2(v.x, v.y), umax2(v.z, v.w));
}
__device__ __forceinline__ float elem(u32x4 v, int j) {
    return __uint_as_float(j == 0 ? v.x : j == 1 ? v.y : j == 2 ? v.z : v.w);
}

__global__ __launch_bounds__(256, 6) void deform_conv2d_kernel(
    const float* __restrict__ inp,     // (B,H,W)
    const float* __restrict__ wgt,     // (K*K)
    const float* __restrict__ off,     // (B, 2*K*K, H, W)
    float* __restrict__ out)           // (B,H,W)
{
    const int idx = blockIdx.x * blockDim.x + threadIdx.x;   // 4 pixels per thread
    const int p4  = idx << 2;
    const int b   = p4 >> 18;            // / (512*512)
    const int hw  = p4 & (HWc - 1);
    const int h   = hw >> 9;
    const int w   = hw & (Wc - 1);       // multiple of 4

    __amdgpu_buffer_rsrc_t orsrc = __builtin_amdgcn_make_buffer_rsrc(
        (void*)(off + (size_t)b * (2 * K * K) * HWc), (short)0,
        (2 * K * K) * HWc * 4, 0x00020000);
    __amdgpu_buffer_rsrc_t irsrc = __builtin_amdgcn_make_buffer_rsrc(
        (void*)(inp + (size_t)b * HWc), (short)0, HWc * 4, 0x00020000);

    // ---- shared 4x7 window: rows h-1..h+2, cols w-1..w+5 (zero-padded) ----
    // Row OOB handled free by SRD bounds check (flat index wraps OOB -> 0).
    // Column wrap-aliasing fixed by 3 masks.
    const int  fbB = ((h - 1) * Wc + (w - 1)) * 4;
    const bool m0 = (w >= 1);
    const bool m5 = (w + 4 < Wc);
    const bool m6 = (w + 5 < Wc);

    float win[4][7];
#pragma unroll
    for (int r = 0; r < 4; ++r) {
        const int rb = fbB + r * Wc * 4;
        const float e0 = bl32 (irsrc, rb,      0);   // col w-1
        const u32x4 md = bl128(irsrc, rb + 4,  0);   // cols w..w+3 (16B aligned)
        const u32x2 e5 = bl64 (irsrc, rb + 20, 0);   // cols w+4,w+5 (8B aligned)
        win[r][0] = m0 ? e0 : 0.f;
        win[r][1] = __uint_as_float(md.x);
        win[r][2] = __uint_as_float(md.y);
        win[r][3] = __uint_as_float(md.z);
        win[r][4] = __uint_as_float(md.w);
        win[r][5] = m5 ? __uint_as_float(e5.x) : 0.f;
        win[r][6] = m6 ? __uint_as_float(e5.y) : 0.f;
    }

    const int hwB = hw * 4;
    float acc[4] = {0.f, 0.f, 0.f, 0.f};

    // k-loop grouped by kernel row (ky = g-1): each group issues its 6 offset
    // loads back-to-back (compiler emits counted vmcnt -> pipelined returns),
    // then one wave-uniform validity branch per group. The per-group branch
    // still fences hoisting across groups (R7/R8 spill mode), but round-trips
    // per wave drop 9 -> 3.
#pragma unroll
    for (int g = 0; g < K; ++g) {
        u32x4 oyu[K], oxu[K];
#pragma unroll
        for (int t = 0; t < K; ++t) {
            const int k = 3 * g + t;
            oyu[t] = bl128(orsrc, hwB, (2 * k)     * HWc * 4);
            oxu[t] = bl128(orsrc, hwB, (2 * k + 1) * HWc * 4);
        }

        // validity of this group's 24 values: f in [0,1) <=> bits < 0x3F800000u
        unsigned vk = 0u;
#pragma unroll
        for (int t = 0; t < K; ++t)
            vk = umax2(vk, umax2(vmax4(oyu[t]), vmax4(oxu[t])));

        if (__all(vk < 0x3F800000u)) {
            // FAST (wave-uniform): floor(y)=h+g-1, floor(x)=w+j+t-1; ly=oy, lx=ox.
            // Window rows g, g+1; col of x0 = j + t.
#pragma unroll
            for (int t = 0; t < K; ++t) {
                const float wkk = wgt[3 * g + t];   // wave-uniform s_load
#pragma unroll
                for (int j = 0; j < 4; ++j) {
                    const int   c  = j + t;
                    const float oy = elem(oyu[t], j);
                    const float ox = elem(oxu[t], j);
                    const float tp = win[g][c]     + ox * (win[g][c + 1]     - win[g][c]);
                    const float bo = win[g + 1][c] + ox * (win[g + 1][c + 1] - win[g + 1][c]);
                    acc[j] += wkk * (tp + oy * (bo - tp));
                }
            }
        } else {
            // GENERAL (never taken for this data; keeps arbitrary-offset correctness)
#pragma unroll
            for (int t = 0; t < K; ++t) {
                const float wkk = wgt[3 * g + t];
                const int ky = g - 1;
                const int kx = t - 1;
#pragma unroll
                for (int j = 0; j < 4; ++j) {
                    const float y = (float)(h + ky)     + elem(oyu[t], j);
                    const float x = (float)(w + j + kx) + elem(oxu[t], j);
                    const float y0f = floorf(y), x0f = floorf(x);
                    const float ly = y - y0f,  lx = x - x0f;
                    const int y0 = (int)y0f, x0 = (int)x0f;

                    const int cb = ((y0 << 9) + x0) * 4;
                    float v00 = bl32(irsrc, cb,              0);
                    float v01 = bl32(irsrc, cb + 4,          0);
                    float v10 = bl32(irsrc, cb + Wc * 4,     0);
                    float v11 = bl32(irsrc, cb + Wc * 4 + 4, 0);
                    const bool vx0 = (unsigned)x0       < (unsigned)Wc;
                    const bool vx1 = (unsigned)(x0 + 1) < (unsigned)Wc;
                    v00 = vx0 ? v00 : 0.f;   v10 = vx0 ? v10 : 0.f;
                    v01 = vx1 ? v01 : 0.f;   v11 = vx1 ? v11 : 0.f;

                    const float top = v00 + lx * (v01 - v00);
                    const float bot = v10 + lx * (v11 - v10);
                    acc[j] += wkk * (top + ly * (bot - top));
                }
            }
        }
    }

    float4 o;
    o.x = acc[0]; o.y = acc[1]; o.z = acc[2]; o.w = acc[3];
    *reinterpret_cast<float4*>(out + p4) = o;    // 16B aligned, coalesced
}

extern "C" void kernel_launch(void* const* d_in, const int* in_sizes, int n_in,
                              void* d_out, int out_size, void* d_ws, size_t ws_size,
                              hipStream_t stream)
{
    const float* inp = (const float*)d_in[0];   // (8,512,512)
    const float* wgt = (const float*)d_in[1];   // (1,1,3,3) = 9 floats
    const float* off = (const float*)d_in[2];   // (8,18,512,512)
    float* out = (float*)d_out;

    const int nthreads = Bc * HWc / 4;          // 4 px per thread
    const int block = 256;
    const int grid  = nthreads / block;         // 2048

    deform_conv2d_kernel<<<grid, block, 0, stream>>>(inp, wgt, off, out);
}

// Round 12
// 33.787 us; speedup vs baseline: 1.4599x; 1.4599x over previous
//
#include <hip/hip_runtime.h>

constexpr int K  = 3;
constexpr int Hc = 512, Wc = 512, Bc = 8;
constexpr int HWc = Hc * Wc;

typedef __attribute__((ext_vector_type(2))) unsigned int u32x2;
typedef __attribute__((ext_vector_type(4))) unsigned int u32x4;

__device__ __forceinline__ float bl32(__amdgpu_buffer_rsrc_t r, int vo, int so) {
    return __uint_as_float(__builtin_amdgcn_raw_buffer_load_b32(r, vo, so, 0));
}
__device__ __forceinline__ u32x2 bl64(__amdgpu_buffer_rsrc_t r, int vo, int so) {
    return __builtin_amdgcn_raw_buffer_load_b64(r, vo, so, 0);
}
__device__ __forceinline__ u32x4 bl128(__amdgpu_buffer_rsrc_t r, int vo, int so) {
    return __builtin_amdgcn_raw_buffer_load_b128(r, vo, so, 0);
}
__device__ __forceinline__ unsigned umax2(unsigned a, unsigned b) { return a > b ? a : b; }
__device__ __forceinline__ float elem2(u32x2 v, int j) {
    return __uint_as_float(j == 0 ? v.x : v.y);
}

__global__ __launch_bounds__(256, 8) void deform_conv2d_kernel(
    const float* __restrict__ inp,     // (B,H,W)
    const float* __restrict__ wgt,     // (K*K)
    const float* __restrict__ off,     // (B, 2*K*K, H, W)
    float* __restrict__ out)           // (B,H,W)
{
    const int idx = blockIdx.x * blockDim.x + threadIdx.x;   // 2 pixels per thread
    const int p2  = idx << 1;
    const int b   = p2 >> 18;            // / (512*512)
    const int hw  = p2 & (HWc - 1);
    const int h   = hw >> 9;
    const int w   = hw & (Wc - 1);       // even

    __amdgpu_buffer_rsrc_t orsrc = __builtin_amdgcn_make_buffer_rsrc(
        (void*)(off + (size_t)b * (2 * K * K) * HWc), (short)0,
        (2 * K * K) * HWc * 4, 0x00020000);
    __amdgpu_buffer_rsrc_t irsrc = __builtin_amdgcn_make_buffer_rsrc(
        (void*)(inp + (size_t)b * HWc), (short)0, HWc * 4, 0x00020000);

    // ---- shared 4x5 window: rows h-1..h+2, cols w-1..w+3 (zero-padded) ----
    // Row OOB handled free by SRD bounds check (negative flat index wraps
    // unsigned -> OOB -> 0). Column wrap-aliasing fixed by 3 masks.
    const int  fbB = ((h - 1) * Wc + (w - 1)) * 4;
    const bool m0 = (w >= 1);            // col w-1
    const bool mz = (w + 2 < Wc);        // col w+2
    const bool mw = (w + 3 < Wc);        // col w+3

    float win[4][5];
#pragma unroll
    for (int r = 0; r < 4; ++r) {
        const int rb = fbB + r * Wc * 4;
        const float e0 = bl32 (irsrc, rb,     0);   // col w-1
        const u32x4 md = bl128(irsrc, rb + 4, 0);   // cols w..w+3 (8B aligned: ok for dword ops)
        win[r][0] = m0 ? e0 : 0.f;
        win[r][1] = __uint_as_float(md.x);
        win[r][2] = __uint_as_float(md.y);
        win[r][3] = mz ? __uint_as_float(md.z) : 0.f;
        win[r][4] = mw ? __uint_as_float(md.w) : 0.f;
    }

    const int hwB = hw * 4;
    float acc[2] = {0.f, 0.f};

    // Per-k structure: the wave-uniform branch fences load hoisting (keeps
    // liveness ~48 VGPR -> fits the (256,8) 64-reg cap, unlike the 4-px R10).
#pragma unroll
    for (int k = 0; k < K * K; ++k) {
        const int ky = k / K - 1;
        const int kx = k % K - 1;
        const int r0 = ky + 1;

        const u32x2 oyu = bl64(orsrc, hwB, (2 * k)     * HWc * 4);
        const u32x2 oxu = bl64(orsrc, hwB, (2 * k + 1) * HWc * 4);

        // validity: f in [0,1) <=> bits < 0x3F800000u (neg/NaN/Inf/>=1 are larger)
        const unsigned vk = umax2(umax2(oyu.x, oyu.y), umax2(oxu.x, oxu.y));

        if (__all(vk < 0x3F800000u)) {
            // FAST (wave-uniform): floor(y)=h+ky, floor(x)=w+j+kx; ly=oy, lx=ox.
#pragma unroll
            for (int j = 0; j < 2; ++j) {
                const int   c  = j + kx + 1;   // 0..3, static after unroll
                const float oy = elem2(oyu, j);
                const float ox = elem2(oxu, j);
                const float tp = win[r0][c]     + ox * (win[r0][c + 1]     - win[r0][c]);
                const float bo = win[r0 + 1][c] + ox * (win[r0 + 1][c + 1] - win[r0 + 1][c]);
                acc[j] += wgt[k] * (tp + oy * (bo - tp));   // wgt[k]: uniform s_load
            }
        } else {
            // GENERAL (never taken for this data; keeps arbitrary-offset correctness)
#pragma unroll
            for (int j = 0; j < 2; ++j) {
                const float y = (float)(h + ky)     + elem2(oyu, j);
                const float x = (float)(w + j + kx) + elem2(oxu, j);
                const float y0f = floorf(y), x0f = floorf(x);
                const float ly = y - y0f,  lx = x - x0f;
                const int y0 = (int)y0f, x0 = (int)x0f;

                const int cb = ((y0 << 9) + x0) * 4;
                float v00 = bl32(irsrc, cb,              0);
                float v01 = bl32(irsrc, cb + 4,          0);
                float v10 = bl32(irsrc, cb + Wc * 4,     0);
                float v11 = bl32(irsrc, cb + Wc * 4 + 4, 0);
                const bool vx0 = (unsigned)x0       < (unsigned)Wc;
                const bool vx1 = (unsigned)(x0 + 1) < (unsigned)Wc;
                v00 = vx0 ? v00 : 0.f;   v10 = vx0 ? v10 : 0.f;
                v01 = vx1 ? v01 : 0.f;   v11 = vx1 ? v11 : 0.f;

                const float top = v00 + lx * (v01 - v00);
                const float bot = v10 + lx * (v11 - v10);
                acc[j] += wgt[k] * (top + ly * (bot - top));
            }
        }
    }

    float2 o;
    o.x = acc[0]; o.y = acc[1];
    *reinterpret_cast<float2*>(out + p2) = o;    // 8B aligned, coalesced
}

extern "C" void kernel_launch(void* const* d_in, const int* in_sizes, int n_in,
                              void* d_out, int out_size, void* d_ws, size_t ws_size,
                              hipStream_t stream)
{
    const float* inp = (const float*)d_in[0];   // (8,512,512)
    const float* wgt = (const float*)d_in[1];   // (1,1,3,3) = 9 floats
    const float* off = (const float*)d_in[2];   // (8,18,512,512)
    float* out = (float*)d_out;

    const int nthreads = Bc * HWc / 2;          // 2 px per thread
    const int block = 256;
    const int grid  = nthreads / block;         // 4096

    deform_conv2d_kernel<<<grid, block, 0, stream>>>(inp, wgt, off, out);
}